// Round 7
// baseline (533.361 us; speedup 1.0000x reference)
//
#include <hip/hip_runtime.h>
#include <hip/hip_cooperative_groups.h>

namespace cg = cooperative_groups;

// VariationalGCNEncoder: 2-layer GCN (512 -> 4 -> [2,2]), N=100k nodes, E=3.2M edges.
//
// R13 = R12 with the back-end (k_csr + k_p2agg1 + k_agg2) collapsed into ONE
// cooperative kernel (grid.sync between phases): ebuf2 (25.6MB round-trip),
// the second ebuf1 pass (12.8MB), nstart/ncnt arrays and 2 launches all
// disappear; the per-bucket sorted src list lives in LDS across BOTH layers.
// Also: lin1 processes 2 rows/wave (ILP) - each wave was one ~900cy dependent
// chain for a single row.
//
//   k_zero  : bcur[b] = b*CAP
//   k_fused : blocks [0,432): tile->LDS 2-pass bucket sort -> ebuf1
//             blocks [432,+6250): hls_raw = x @ W1 (2 rows per wave, float4)
//   k_coop  : per-bucket (cooperative, 782 blocks):
//             (i) stage ebuf1 + node hist + scan; rescale own hls *= dinv
//             (ii) grid.sync
//             (iii) rank-sort srcs in LDS; layer-1 gather (4thr/node) -> ts
//             (iv) grid.sync
//             (v) layer-2 gather from SAME LDS srcs -> mu/logstd -> out

constexpr int N_NODES = 100000;
constexpr int N_EDGES = 3200000;
constexpr int IN_CH   = 512;
constexpr int BK_SH   = 7;                       // 128 nodes per bucket
constexpr int BK_N    = 1 << BK_SH;              // 128
constexpr int KC      = (N_NODES + BK_N - 1) / BK_N;    // 782
constexpr int CAP     = 4608;                    // per-bucket capacity (mean 4092)
constexpr int T_TILE  = 7424;                    // edges per part1 tile (29KB LDS)
constexpr int NT_P1   = (N_EDGES + T_TILE - 1) / T_TILE;  // 432
constexpr int ROWS_PB = 16;                      // lin1 rows per 512-thread block
constexpr int NB_LIN  = N_NODES / ROWS_PB;       // 6250 (exact)

__global__ __launch_bounds__(256) void k_zero(int* __restrict__ bcur) {
    int i = blockIdx.x * blockDim.x + threadIdx.x;
    if (i < KC) bcur[i] = i * CAP;
}

// Fused: part1 bucket sort (blocks < NT_P1) + lin1 raw GEMV (remaining blocks).
__global__ __launch_bounds__(512) void k_fused(const int* __restrict__ src,
                                               const int* __restrict__ dst,
                                               int* __restrict__ bcur,
                                               int* __restrict__ ebuf1,
                                               const float* __restrict__ x,
                                               const float* __restrict__ W1,
                                               float* __restrict__ h) {
    __shared__ int sorted[T_TILE];   // 29 KB: bucket-sorted packed edges of this tile
    __shared__ int tstart[KC];       // tile-local exclusive bucket starts
    __shared__ int cur[KC];          // pass A: histogram; pass B: ranking cursor
    __shared__ int gbase[KC];        // reserved global base per bucket

    if (blockIdx.x < NT_P1) {
        // ---------------- part1: tile-wise bucket sort ----------------
        int tid = threadIdx.x;
        int e0 = blockIdx.x * T_TILE;
        int tcnt = min(T_TILE, N_EDGES - e0);

        for (int i = tid; i < KC; i += 512) cur[i] = 0;
        __syncthreads();

        // pass A: histogram dst buckets
        for (int j = tid; j < tcnt; j += 512) {
            int d = dst[e0 + j];
            if ((unsigned)d < (unsigned)N_NODES) atomicAdd(&cur[d >> BK_SH], 1);
        }
        __syncthreads();

        // scan cur -> tstart (782 entries, 2 per thread; temp in sorted[0..511])
        {
            int i0 = 2 * tid, i1 = 2 * tid + 1;
            int a0 = (i0 < KC) ? cur[i0] : 0;
            int a1 = (i1 < KC) ? cur[i1] : 0;
            int s = a0 + a1;
            sorted[tid] = s;
            __syncthreads();
            for (int off = 1; off < 512; off <<= 1) {
                int t = (tid >= off) ? sorted[tid - off] : 0;
                __syncthreads();
                sorted[tid] += t;
                __syncthreads();
            }
            int excl = sorted[tid] - s;
            if (i0 < KC) tstart[i0] = excl;
            if (i1 < KC) tstart[i1] = excl + a0;
            __syncthreads();
        }

        // reserve global space per bucket; convert cur -> ranking cursor
        for (int i = tid; i < KC; i += 512) {
            int c = cur[i];
            gbase[i] = c ? atomicAdd(&bcur[i], c) : 0;
            cur[i] = tstart[i];
        }
        __syncthreads();

        // pass B: rank + scatter into LDS (packed (s<<7)|(d&127); s < 2^17)
        for (int j = tid; j < tcnt; j += 512) {
            int s = src[e0 + j], d = dst[e0 + j];
            if ((unsigned)s < (unsigned)N_NODES && (unsigned)d < (unsigned)N_NODES) {
                int b = d >> BK_SH;
                int r = atomicAdd(&cur[b], 1);
                sorted[r] = (s << BK_SH) | (d & (BK_N - 1));
            }
        }
        __syncthreads();

        // writeout: wave-per-bucket, contiguous LDS run -> contiguous global segment
        int wv = tid >> 6, ln = tid & 63;
        for (int b = wv; b < KC; b += 8) {
            int st = tstart[b];
            int c  = cur[b] - st;               // bucket count in this tile
            int gb = gbase[b];
            int avail = (b + 1) * CAP - gb;     // capacity guard (unreachable statistically)
            if (avail < c) c = max(avail, 0);
            for (int j = ln; j < c; j += 64)
                ebuf1[gb + j] = sorted[st + j];
        }
    } else {
        // ------- lin1: 2 rows per wave for load ILP (all rows valid: 16|100000) --
        int wave = threadIdx.x >> 6, lane = threadIdx.x & 63;
        int row0 = (blockIdx.x - NT_P1) * ROWS_PB + wave * 2;
        int row1 = row0 + 1;
        const float4* xa = (const float4*)(x + (size_t)row0 * IN_CH);
        const float4* xb = (const float4*)(x + (size_t)row1 * IN_CH);
        const float4* w4 = (const float4*)W1;
        float4 accA = make_float4(0.f, 0.f, 0.f, 0.f);
        float4 accB = make_float4(0.f, 0.f, 0.f, 0.f);
#pragma unroll
        for (int j = 0; j < 2; ++j) {
            int idx = lane + 64 * j;
            float4 va = xa[idx];
            float4 vb = xb[idx];
            int kb = 4 * idx;
            float4 wa = w4[kb + 0], wb = w4[kb + 1], wc = w4[kb + 2], wd = w4[kb + 3];
            accA.x += va.x * wa.x + va.y * wb.x + va.z * wc.x + va.w * wd.x;
            accA.y += va.x * wa.y + va.y * wb.y + va.z * wc.y + va.w * wd.y;
            accA.z += va.x * wa.z + va.y * wb.z + va.z * wc.z + va.w * wd.z;
            accA.w += va.x * wa.w + va.y * wb.w + va.z * wc.w + va.w * wd.w;
            accB.x += vb.x * wa.x + vb.y * wb.x + vb.z * wc.x + vb.w * wd.x;
            accB.y += vb.x * wa.y + vb.y * wb.y + vb.z * wc.y + vb.w * wd.y;
            accB.z += vb.x * wa.z + vb.y * wb.z + vb.z * wc.z + vb.w * wd.z;
            accB.w += vb.x * wa.w + vb.y * wb.w + vb.z * wc.w + vb.w * wd.w;
        }
#pragma unroll
        for (int off = 32; off > 0; off >>= 1) {
            accA.x += __shfl_down(accA.x, off);
            accA.y += __shfl_down(accA.y, off);
            accA.z += __shfl_down(accA.z, off);
            accA.w += __shfl_down(accA.w, off);
            accB.x += __shfl_down(accB.x, off);
            accB.y += __shfl_down(accB.y, off);
            accB.z += __shfl_down(accB.z, off);
            accB.w += __shfl_down(accB.w, off);
        }
        if (lane == 0) {
            ((float4*)h)[row0] = accA;
            ((float4*)h)[row1] = accB;
        }
    }
}

// Cooperative back-end: CSR build + hls rescale | sync | sort + layer-1 | sync |
// layer-2. Sorted src list stays in LDS across both layers. NO early returns
// (every thread must reach both grid.sync calls).
__global__ __launch_bounds__(512) void k_coop(const int* __restrict__ bcur,
                                              const int* __restrict__ ebuf1,
                                              float* __restrict__ hls,
                                              const float* __restrict__ b1,
                                              const float* __restrict__ Wmu,
                                              const float* __restrict__ Wls,
                                              float* __restrict__ ts,
                                              const float* __restrict__ bmu,
                                              const float* __restrict__ bls,
                                              float* __restrict__ out) {
    __shared__ int stag[CAP];        // 18 KB: staged packed edges (one global read)
    __shared__ int sorted[CAP];      // 18 KB: node-sorted src indices (both layers)
    __shared__ int hist[BK_N], excl_l[BK_N], cnt_l[BK_N], curx[BK_N];
    cg::grid_group grid = cg::this_grid();
    int b = blockIdx.x, tid = threadIdx.x;
    int base = b * CAP;
    int cnt = min(bcur[b] - base, CAP);

    if (tid < BK_N) hist[tid] = 0;
    __syncthreads();
    // (i) stage + node histogram
    for (int j = tid; j < cnt; j += 512) {
        int e = ebuf1[base + j];
        stag[j] = e;
        atomicAdd(&hist[e & (BK_N - 1)], 1);
    }
    __syncthreads();
    // scan 128 entries
    if (tid < BK_N) excl_l[tid] = hist[tid];
    __syncthreads();
    for (int off = 1; off < BK_N; off <<= 1) {
        int t = (tid < BK_N && tid >= off) ? excl_l[tid - off] : 0;
        __syncthreads();
        if (tid < BK_N) excl_l[tid] += t;
        __syncthreads();
    }
    if (tid < BK_N) {
        int v = hist[tid];
        int ex = excl_l[tid] - v;            // exclusive
        excl_l[tid] = ex;
        curx[tid]   = ex;
        cnt_l[tid]  = v;
        int node = b * BK_N + tid;
        if (node < N_NODES) {
            float di = rsqrtf((float)(v + 1));   // +1 self loop
            float4* h4 = (float4*)hls;           // deferred lin1 scaling
            float4 hv = h4[node];
            h4[node] = make_float4(hv.x * di, hv.y * di, hv.z * di, hv.w * di);
        }
    }
    __syncthreads();
    // rank + scatter srcs into LDS (store src only; dst implied by position)
    for (int j = tid; j < cnt; j += 512) {
        int e = stag[j];
        int r = atomicAdd(&curx[e & (BK_N - 1)], 1);
        sorted[r] = e >> BK_SH;
    }

    // (ii) all blocks: hls fully rescaled, own sorted[] complete
    grid.sync();

    // (iii) layer-1 gather: 4 threads per node, srcs from LDS, hls pre-scaled
    int ln = tid >> 2, r = tid & 3;              // 128 nodes x 4 threads
    int node = b * BK_N + ln;
    bool valid = node < N_NODES;                 // quad-uniform
    int st = excl_l[ln], c = cnt_l[ln];
    const float4* g4 = (const float4*)hls;
    if (valid) {
        float4 a0 = make_float4(0.f, 0.f, 0.f, 0.f);
        float4 a1 = make_float4(0.f, 0.f, 0.f, 0.f);
        int j = st + r, last = st + c;
        for (; j + 4 < last; j += 8) {
            float4 f0 = g4[sorted[j]];
            float4 f1 = g4[sorted[j + 4]];
            a0.x += f0.x; a0.y += f0.y; a0.z += f0.z; a0.w += f0.w;
            a1.x += f1.x; a1.y += f1.y; a1.z += f1.z; a1.w += f1.w;
        }
        if (j < last) {
            float4 f = g4[sorted[j]];
            a0.x += f.x; a0.y += f.y; a0.z += f.z; a0.w += f.w;
        }
        a0.x += a1.x; a0.y += a1.y; a0.z += a1.z; a0.w += a1.w;
        a0.x += __shfl_xor(a0.x, 1); a0.y += __shfl_xor(a0.y, 1);
        a0.z += __shfl_xor(a0.z, 1); a0.w += __shfl_xor(a0.w, 1);
        a0.x += __shfl_xor(a0.x, 2); a0.y += __shfl_xor(a0.y, 2);
        a0.z += __shfl_xor(a0.z, 2); a0.w += __shfl_xor(a0.w, 2);
        if (r == 0) {
            float di = rsqrtf((float)(c + 1));
            float4 self = g4[node];
            float h0 = fmaxf((a0.x + self.x) * di + b1[0], 0.f);
            float h1 = fmaxf((a0.y + self.y) * di + b1[1], 0.f);
            float h2 = fmaxf((a0.z + self.z) * di + b1[2], 0.f);
            float h3 = fmaxf((a0.w + self.w) * di + b1[3], 0.f);
            float4 o;
            o.x = (h0 * Wmu[0] + h1 * Wmu[2] + h2 * Wmu[4] + h3 * Wmu[6]) * di;
            o.y = (h0 * Wmu[1] + h1 * Wmu[3] + h2 * Wmu[5] + h3 * Wmu[7]) * di;
            o.z = (h0 * Wls[0] + h1 * Wls[2] + h2 * Wls[4] + h3 * Wls[6]) * di;
            o.w = (h0 * Wls[1] + h1 * Wls[3] + h2 * Wls[5] + h3 * Wls[7]) * di;
            ((float4*)ts)[node] = o;
        }
    }

    // (iv) all ts written
    grid.sync();

    // (v) layer-2 gather on ts, same LDS srcs -> mu (out[0..2N)), logstd (out[2N..4N))
    if (valid) {
        const float4* t4 = (const float4*)ts;
        float4 a0 = make_float4(0.f, 0.f, 0.f, 0.f);
        float4 a1 = make_float4(0.f, 0.f, 0.f, 0.f);
        int j = st + r, last = st + c;
        for (; j + 4 < last; j += 8) {
            float4 f0 = t4[sorted[j]];
            float4 f1 = t4[sorted[j + 4]];
            a0.x += f0.x; a0.y += f0.y; a0.z += f0.z; a0.w += f0.w;
            a1.x += f1.x; a1.y += f1.y; a1.z += f1.z; a1.w += f1.w;
        }
        if (j < last) {
            float4 f = t4[sorted[j]];
            a0.x += f.x; a0.y += f.y; a0.z += f.z; a0.w += f.w;
        }
        a0.x += a1.x; a0.y += a1.y; a0.z += a1.z; a0.w += a1.w;
        a0.x += __shfl_xor(a0.x, 1); a0.y += __shfl_xor(a0.y, 1);
        a0.z += __shfl_xor(a0.z, 1); a0.w += __shfl_xor(a0.w, 1);
        a0.x += __shfl_xor(a0.x, 2); a0.y += __shfl_xor(a0.y, 2);
        a0.z += __shfl_xor(a0.z, 2); a0.w += __shfl_xor(a0.w, 2);
        if (r == 0) {
            float di = rsqrtf((float)(c + 1));
            float4 self = t4[node];
            float2 mu = make_float2((a0.x + self.x) * di + bmu[0],
                                    (a0.y + self.y) * di + bmu[1]);
            float2 ls = make_float2((a0.z + self.z) * di + bls[0],
                                    (a0.w + self.w) * di + bls[1]);
            ((float2*)out)[node] = mu;
            ((float2*)(out + 2 * N_NODES))[node] = ls;
        }
    }
}

extern "C" void kernel_launch(void* const* d_in, const int* in_sizes, int n_in,
                              void* d_out, int out_size, void* d_ws, size_t ws_size,
                              hipStream_t stream) {
    const float* x    = (const float*)d_in[0];
    const int*   ei   = (const int*)d_in[1];    // [2, E] int32: src row then dst row
    const float* W1   = (const float*)d_in[2];
    const float* b1   = (const float*)d_in[3];
    const float* Wmu  = (const float*)d_in[4];
    const float* bmu  = (const float*)d_in[5];
    const float* Wls  = (const float*)d_in[6];
    const float* bls  = (const float*)d_in[7];
    float* out = (float*)d_out;

    const int* srcp = ei;
    const int* dstp = ei + N_EDGES;

    // workspace layout (~18 MB)
    char* p = (char*)d_ws;
    float* hls    = (float*)p;  p += (size_t)N_NODES * 16;
    float* ts     = (float*)p;  p += (size_t)N_NODES * 16;
    int*   bcur   = (int*)p;    p += (size_t)KC * 4;
    int*   ebuf1  = (int*)p;    p += (size_t)KC * CAP * 4;   // 14.4 MB

    const int TB = 256;

    k_zero <<<(KC + TB - 1) / TB, TB, 0, stream>>>(bcur);
    k_fused<<<NT_P1 + NB_LIN, 512, 0, stream>>>(srcp, dstp, bcur, ebuf1, x, W1, hls);

    void* args[] = { (void*)&bcur, (void*)&ebuf1, (void*)&hls, (void*)&b1,
                     (void*)&Wmu, (void*)&Wls, (void*)&ts, (void*)&bmu,
                     (void*)&bls, (void*)&out };
    hipLaunchCooperativeKernel((const void*)k_coop, dim3(KC), dim3(512),
                               args, 0, stream);
}